// Round 3
// baseline (331.986 us; speedup 1.0000x reference)
//
#include <hip/hip_runtime.h>

// ---------------------------------------------------------------------------
// CanonicalLinear: out[b,c] = sum_n factor[n] * (x @ W[n]^T + b[n])[b,c]
// Collapse heads: Weff = sum_n factor[n]*W[n] (C x D), beff = sum_n factor[n]*b[n]
// then out = x @ Weff^T + beff  -- single bf16 MFMA GEMM (m97 structure).
// Round 3: prep rewritten for deep MLP + 16-B stores (was issue-bound at
//          1.5 TB/s with 20k tiny blocks); GEMM unchanged (XOR-swizzled LDS,
//          XCD-aware block swizzle).
// ---------------------------------------------------------------------------

#define MDIM 8192
#define KDIM 2048
#define NDIM 2048
#define NHEADS 8

#define BM 128
#define BN 128
#define BK 64

using bf16x8 = __attribute__((ext_vector_type(8))) short;
using f32x4  = __attribute__((ext_vector_type(4))) float;

__device__ __forceinline__ unsigned short f2bf(float x) {
    unsigned int u = __float_as_uint(x);
    u += 0x7FFFu + ((u >> 16) & 1u);
    return (unsigned short)(u >> 16);
}

__device__ __forceinline__ void async_load16(const void* g, void* l) {
    __builtin_amdgcn_global_load_lds(
        (const __attribute__((address_space(1))) unsigned int*)g,
        (__attribute__((address_space(3))) unsigned int*)l,
        16, 0, 0);
}

// --- fused prep, flat 4096 blocks x 256 threads -----------------------------
// every thread:  x-cast of 16 elems (4x float4 in flight, 2x 16-B stores)
// gtid < 524288: W-reduce of 8 elems (16x float4 in flight, 1x 16-B store)
// gtid < 2048:   beff[c] = sum_n f[n]*b[n,c]
__global__ __launch_bounds__(256) void prep_kernel(
    const float* __restrict__ x,
    const float* __restrict__ W,
    const float* __restrict__ b,
    const float* __restrict__ factor,
    unsigned short* __restrict__ xbf,
    unsigned short* __restrict__ Wbf,
    float* __restrict__ beff) {
    const int gtid = blockIdx.x * 256 + threadIdx.x;   // 0 .. 1,048,575

    // ---- x cast: 16,777,216 elems / 16 = exactly 1,048,576 threads --------
    {
        size_t base = (size_t)gtid * 16;
        float4 v0 = *reinterpret_cast<const float4*>(x + base);
        float4 v1 = *reinterpret_cast<const float4*>(x + base + 4);
        float4 v2 = *reinterpret_cast<const float4*>(x + base + 8);
        float4 v3 = *reinterpret_cast<const float4*>(x + base + 12);
        union { unsigned short u[16]; uint4 q[2]; } o;
        o.u[0]  = f2bf(v0.x); o.u[1]  = f2bf(v0.y); o.u[2]  = f2bf(v0.z); o.u[3]  = f2bf(v0.w);
        o.u[4]  = f2bf(v1.x); o.u[5]  = f2bf(v1.y); o.u[6]  = f2bf(v1.z); o.u[7]  = f2bf(v1.w);
        o.u[8]  = f2bf(v2.x); o.u[9]  = f2bf(v2.y); o.u[10] = f2bf(v2.z); o.u[11] = f2bf(v2.w);
        o.u[12] = f2bf(v3.x); o.u[13] = f2bf(v3.y); o.u[14] = f2bf(v3.z); o.u[15] = f2bf(v3.w);
        *reinterpret_cast<uint4*>(xbf + base)     = o.q[0];
        *reinterpret_cast<uint4*>(xbf + base + 8) = o.q[1];
    }

    // ---- W reduce: 4,194,304 elems / 8 = 524,288 threads (blocks 0..2047) --
    if (gtid < 524288) {
        const size_t CD = (size_t)NDIM * KDIM;
        size_t base = (size_t)gtid * 8;
        float f[NHEADS];
#pragma unroll
        for (int n = 0; n < NHEADS; ++n) f[n] = factor[n];
        float a0 = 0.f, a1 = 0.f, a2 = 0.f, a3 = 0.f;
        float a4 = 0.f, a5 = 0.f, a6 = 0.f, a7 = 0.f;
#pragma unroll
        for (int n = 0; n < NHEADS; ++n) {
            float4 lo = *reinterpret_cast<const float4*>(W + (size_t)n * CD + base);
            float4 hi = *reinterpret_cast<const float4*>(W + (size_t)n * CD + base + 4);
            a0 += f[n] * lo.x; a1 += f[n] * lo.y; a2 += f[n] * lo.z; a3 += f[n] * lo.w;
            a4 += f[n] * hi.x; a5 += f[n] * hi.y; a6 += f[n] * hi.z; a7 += f[n] * hi.w;
        }
        union { unsigned short u[8]; uint4 q; } o;
        o.u[0] = f2bf(a0); o.u[1] = f2bf(a1); o.u[2] = f2bf(a2); o.u[3] = f2bf(a3);
        o.u[4] = f2bf(a4); o.u[5] = f2bf(a5); o.u[6] = f2bf(a6); o.u[7] = f2bf(a7);
        *reinterpret_cast<uint4*>(Wbf + base) = o.q;
    }

    // ---- bias reduce: 2048 threads ----------------------------------------
    if (gtid < NDIM) {
        float s = 0.f;
#pragma unroll
        for (int n = 0; n < NHEADS; ++n) s += factor[n] * b[(size_t)n * NDIM + gtid];
        beff[gtid] = s;
    }
}

// --- GEMM: out[m,c] = sum_k A[m,k]*B[c,k] + bias[c]  (B^T layout) -----------
__global__ __launch_bounds__(256) void gemm_bt_kernel(
    const unsigned short* __restrict__ A,   // xbf  [MDIM][KDIM]
    const unsigned short* __restrict__ B,   // Wbf  [NDIM][KDIM]
    const float* __restrict__ bias,         // beff [NDIM]
    float* __restrict__ C)                  // out  [MDIM][NDIM] fp32
{
    __shared__ unsigned short As[BM * BK];  // 16 KB, unpadded (global_load_lds)
    __shared__ unsigned short Bs[BN * BK];  // 16 KB

    const int tid  = threadIdx.x;
    const int lane = tid & 63;
    const int w    = tid >> 6;      // wave 0..3
    const int m16  = lane & 15;
    const int quad = lane >> 4;     // 0..3

    // XCD-aware swizzle: xcd = bid&7 owns N-tiles {2*xcd, 2*xcd+1} (1 MB of B
    // -> L2-resident per XCD); A streams through once per XCD.
    const int bid = blockIdx.x;
    const int g   = bid >> 3;
    const int nt  = (bid & 7) * 2 + (g & 1);
    const int mt  = g >> 1;
    const int blockN0 = nt * BN;
    const int blockM0 = mt * BM;

    const int wr = (w >> 1) * 64;   // wave's row quadrant in tile
    const int wc = (w & 1) * 64;    // wave's col quadrant

    // staging: lane deposits 16 B at LDS slot (srow, lane&7)  [HW-fixed order];
    // XOR-swizzle the GLOBAL column group so LDS group gl holds global group
    // gl ^ (row&7) -> fragment reads spread across all 8 bank-groups.
    const int srow = lane >> 3;                    // 0..7
    const int scol = ((lane & 7) ^ srow) * 8;      // swizzled global bf16 col
    const unsigned short* aP[4];
    const unsigned short* bP[4];
    unsigned short* aL[4];
    unsigned short* bL[4];
#pragma unroll
    for (int i = 0; i < 4; ++i) {
        int r = i * 32 + w * 8;
        aP[i] = A + (size_t)(blockM0 + r + srow) * KDIM + scol;
        bP[i] = B + (size_t)(blockN0 + r + srow) * KDIM + scol;
        aL[i] = As + (size_t)r * BK;               // wave-uniform LDS base
        bL[i] = Bs + (size_t)r * BK;
    }

    f32x4 acc[4][4] = {};

    for (int k0 = 0; k0 < KDIM; k0 += BK) {
#pragma unroll
        for (int i = 0; i < 4; ++i) {
            async_load16(aP[i], aL[i]);
            async_load16(bP[i], bL[i]);
            aP[i] += BK; bP[i] += BK;
        }
        __syncthreads();

#pragma unroll
        for (int kk = 0; kk < BK; kk += 32) {
            bf16x8 af[4], bfr[4];
#pragma unroll
            for (int rt = 0; rt < 4; ++rt) {
                int row = wr + rt * 16 + m16;
                int gA = ((kk >> 3) + quad) ^ (row & 7);   // un-swizzle
                af[rt] = *reinterpret_cast<const bf16x8*>(&As[(size_t)row * BK + gA * 8]);
            }
#pragma unroll
            for (int ct = 0; ct < 4; ++ct) {
                int row = wc + ct * 16 + m16;
                int gB = ((kk >> 3) + quad) ^ (row & 7);
                bfr[ct] = *reinterpret_cast<const bf16x8*>(&Bs[(size_t)row * BK + gB * 8]);
            }
#pragma unroll
            for (int rt = 0; rt < 4; ++rt)
#pragma unroll
                for (int ct = 0; ct < 4; ++ct)
                    acc[rt][ct] = __builtin_amdgcn_mfma_f32_16x16x32_bf16(
                        af[rt], bfr[ct], acc[rt][ct], 0, 0, 0);
        }
        __syncthreads();
    }

    // epilogue: C/D layout col=lane&15, row=quad*4+reg (verified m89/m91)
    float bv[4];
#pragma unroll
    for (int ct = 0; ct < 4; ++ct) bv[ct] = bias[blockN0 + wc + ct * 16 + m16];
#pragma unroll
    for (int rt = 0; rt < 4; ++rt) {
        int row0 = blockM0 + wr + rt * 16 + quad * 4;
#pragma unroll
        for (int ct = 0; ct < 4; ++ct) {
            int col = blockN0 + wc + ct * 16 + m16;
#pragma unroll
            for (int r = 0; r < 4; ++r)
                C[(size_t)(row0 + r) * NDIM + col] = acc[rt][ct][r] + bv[ct];
        }
    }
}

extern "C" void kernel_launch(void* const* d_in, const int* in_sizes, int n_in,
                              void* d_out, int out_size, void* d_ws, size_t ws_size,
                              hipStream_t stream) {
    const float* x      = (const float*)d_in[0];   // [8192][2048]
    const float* W      = (const float*)d_in[1];   // [8][2048][2048]
    const float* b      = (const float*)d_in[2];   // [8][2048]
    const float* factor = (const float*)d_in[3];   // [8]
    float* out = (float*)d_out;                    // [8192][2048]

    unsigned short* xbf  = (unsigned short*)d_ws;                         // 33,554,432 B
    unsigned short* Wbf  = (unsigned short*)((char*)d_ws + 33554432);     //  8,388,608 B
    float*          beff = (float*)((char*)d_ws + 33554432 + 8388608);    //      8,192 B

    prep_kernel<<<dim3(4096), dim3(256), 0, stream>>>(x, W, b, factor, xbf, Wbf, beff);
    gemm_bt_kernel<<<dim3(1024), dim3(256), 0, stream>>>(xbf, Wbf, beff, out);
}